// Round 6
// baseline (4318.950 us; speedup 1.0000x reference)
//
#include <hip/hip_runtime.h>
#include <stdint.h>

#define B_ 128
#define T_ 512
#define H_ 256
#define CH 128           // timesteps per chunk (xz slab = 32 MB)
#define RB 8             // rec blocks per layer (16 batch rows each)

typedef short bf16x8 __attribute__((ext_vector_type(8)));   // 8 bf16 = 4 VGPRs
typedef float f32x4 __attribute__((ext_vector_type(4)));
typedef int   i32x4 __attribute__((ext_vector_type(4)));

__device__ __forceinline__ unsigned short f2bf(float f) {
    union { float f; uint32_t u; } v; v.f = f;
    uint32_t u = v.u;
    return (unsigned short)((u + 0x7FFFu + ((u >> 16) & 1u)) >> 16);  // RNE
}
__device__ __forceinline__ float bf2f(unsigned int b) {
    union { uint32_t u; float f; } v; v.u = (b & 0xFFFFu) << 16; return v.f;
}
__device__ __forceinline__ float sigm(float x) { return 1.0f / (1.0f + __expf(-x)); }
__device__ __forceinline__ float tanh_(float x) { return 1.0f - 2.0f / (__expf(2.0f * x) + 1.0f); }

// ---- prep: x[b][t][f] fp32 -> xbf[t][b][f] bf16 ----
__global__ void k_prep_x(const float* __restrict__ x, unsigned short* __restrict__ xbf) {
    int idx = blockIdx.x * blockDim.x + threadIdx.x;   // over B*T*F/4
    int f4 = idx & 63;
    int t = (idx >> 6) & 511;
    int b = idx >> 15;
    float4 v = *(const float4*)(x + ((size_t)b * T_ + t) * H_ + f4 * 4);
    ushort4 o;
    o.x = f2bf(v.x); o.y = f2bf(v.y); o.z = f2bf(v.z); o.w = f2bf(v.w);
    *(ushort4*)(xbf + ((size_t)t * B_ + b) * H_ + f4 * 4) = o;
}

// ---- prep: in [256][1024] fp32 -> out[col][k] bf16 ----
__global__ void k_prep_w(const float* __restrict__ in, unsigned short* __restrict__ out) {
    int idx = blockIdx.x * blockDim.x + threadIdx.x;   // 1024*256
    int k = idx & 255; int col = idx >> 8;
    out[(size_t)col * 256 + k] = f2bf(in[(size_t)k * 1024 + col]);
}

__global__ void k_prep_wd(const float* __restrict__ Wd, unsigned short* __restrict__ Wdt) {
    int idx = blockIdx.x * blockDim.x + threadIdx.x;   // 256*256
    int k = idx & 255; int col = idx >> 8;
    Wdt[(size_t)col * 256 + k] = f2bf(Wd[(size_t)k * 256 + col]);
}

// ---- absmax of U (262144 fp32) -> slot (float bits via int atomicMax) ----
__global__ void k_umax(const float* __restrict__ in, float* __restrict__ slot) {
    float m = 0.f;
    for (int i = blockIdx.x * blockDim.x + threadIdx.x; i < 262144; i += gridDim.x * blockDim.x)
        m = fmaxf(m, fabsf(in[i]));
#pragma unroll
    for (int off = 1; off < 64; off <<= 1) m = fmaxf(m, __shfl_xor(m, off));
    if ((threadIdx.x & 63) == 0) atomicMax((int*)slot, __float_as_int(m));
}

// ---- quantize U: in [256][1024] fp32 -> out[col][k] i8 ----
__global__ void k_prep_u(const float* __restrict__ in, const float* __restrict__ umax,
                         signed char* __restrict__ out) {
    int idx = blockIdx.x * blockDim.x + threadIdx.x;   // 1024*256
    int k = idx & 255; int col = idx >> 8;
    float s = 127.f / *umax;
    float v = in[(size_t)k * 1024 + col] * s;
    out[(size_t)col * 256 + k] = (signed char)__float2int_rn(fminf(fmaxf(v, -127.f), 127.f));
}

// ---- input-projection GEMM for one 128-t chunk ----
// xz swizzle (per-lane contiguous for k_rec):
// row = rb*16 + q*4 + r (rb<8,q<4,r<4); col = g*256 + w*32 + s*16 + l15; n = g*2+s
// elem = ((((tl*8 + rb)*8 + w)*4 + q)*16 + l15)*32 + n*4 + r
__global__ __launch_bounds__(256, 2) void k_gemm(
    const unsigned short* __restrict__ A, const unsigned short* __restrict__ Bt,
    const float* __restrict__ bias, unsigned short* __restrict__ xz) {
    const int tl = blockIdx.x >> 2, nq = blockIdx.x & 3;   // nq = gate g
    const int tid = threadIdx.x;
    const int wave = tid >> 6, lane = tid & 63, quad = lane >> 4, l15 = lane & 15;
    const f32x4 zero = {0.f, 0.f, 0.f, 0.f};
    f32x4 acc[2][16];
#pragma unroll
    for (int m = 0; m < 2; ++m)
#pragma unroll
        for (int n = 0; n < 16; ++n) acc[m][n] = zero;

#pragma unroll
    for (int kt = 0; kt < 8; ++kt) {
        bf16x8 a0 = *(const bf16x8*)(A + ((size_t)(tl * 128 + wave * 32 + l15)) * 256 + kt * 32 + quad * 8);
        bf16x8 a1 = *(const bf16x8*)(A + ((size_t)(tl * 128 + wave * 32 + 16 + l15)) * 256 + kt * 32 + quad * 8);
#pragma unroll
        for (int ntl = 0; ntl < 16; ++ntl) {
            bf16x8 b = *(const bf16x8*)(Bt + ((size_t)(nq * 256 + ntl * 16 + l15)) * 256 + kt * 32 + quad * 8);
            acc[0][ntl] = __builtin_amdgcn_mfma_f32_16x16x32_bf16(a0, b, acc[0][ntl], 0, 0, 0);
            acc[1][ntl] = __builtin_amdgcn_mfma_f32_16x16x32_bf16(a1, b, acc[1][ntl], 0, 0, 0);
        }
    }
#pragma unroll
    for (int ntl = 0; ntl < 16; ++ntl) {
        int c0 = nq * 256 + ntl * 16;
        float bv = bias[c0 + l15];
        int wI = ntl >> 1, sI = ntl & 1, n = nq * 2 + sI;
#pragma unroll
        for (int mt = 0; mt < 2; ++mt) {
            int rb = wave * 2 + mt;
            unsigned long long pk = 0;
#pragma unroll
            for (int r = 0; r < 4; ++r)
                pk |= ((unsigned long long)f2bf(acc[mt][ntl][r] + bv)) << (16 * r);
            size_t off = ((((size_t)(tl * 8 + rb) * 8 + wI) * 4 + quad) * 16 + l15) * 32 + n * 4;
            *(unsigned long long*)(xz + off) = pk;
        }
    }
}

__device__ __forceinline__ float xzext(const unsigned int* xd, int e) {
    unsigned int d = xd[e >> 1];
    union { unsigned int u; float f; } vv;
    vv.u = (e & 1) ? (d & 0xFFFF0000u) : (d << 16);
    return vv.f;
}

// ---- LSTM recurrence chunk: i8 MFMA, U truly register-resident ----
// grid = 8 blocks x 512 thr (8 waves, 2/SIMD); block owns rows [16*blk,16*blk+16).
// Wave w owns cols w*32+s*16+l15 of ALL 4 gates (tiles n=g*2+s) -> gates for a
// given (row,col) land in ONE lane; no z-exchange, no LDS round trip.
__global__ __launch_bounds__(512, 2) void k_rec(
    const signed char* __restrict__ Ui8,     // [1024][256] i8
    const unsigned short* __restrict__ xz,   // chunk, swizzled
    const float* __restrict__ uscale,
    unsigned short* __restrict__ hout,       // [T][128][256] bf16
    float* __restrict__ cstate,              // [8][512][8]
    int t0) {
    __shared__ signed char hbuf[2][16 * 272];            // i8 h ping-pong (8.7 KB)
    __shared__ unsigned short hstage[2][2][16][256];     // bf16 h stage (32 KB)
    const int blk = blockIdx.x;
    const int tid = threadIdx.x;
    const int w = tid >> 6, lane = tid & 63, quad = lane >> 4, l15 = lane & 15;

    // U fragments: 8 n-tiles x 4 kt x int4 = 128 VGPR, resident all steps
    i32x4 Bf[8][4];
#pragma unroll
    for (int n = 0; n < 8; ++n) {
        int col = (n >> 1) * 256 + w * 32 + (n & 1) * 16 + l15;
#pragma unroll
        for (int kt = 0; kt < 4; ++kt)
            Bf[n][kt] = *(const i32x4*)(Ui8 + (size_t)col * 256 + kt * 64 + quad * 16);
    }

    float cst[8];
    if (t0 > 0) {
        for (int i = tid; i < 4096; i += 512) {
            int row = i >> 8, colx = i & 255;
            float h = bf2f(hout[((size_t)(t0 - 1) * 128 + blk * 16 + row) * 256 + colx]);
            hbuf[0][row * 272 + colx] = (signed char)__float2int_rn(h * 127.f);
        }
#pragma unroll
        for (int j = 0; j < 8; ++j) cst[j] = cstate[((size_t)blk * 512 + tid) * 8 + j];
    } else {
        for (int i = tid; i < 1088; i += 512) ((int*)hbuf[0])[i] = 0;
#pragma unroll
        for (int j = 0; j < 8; ++j) cst[j] = 0.f;
    }
    const float SUH = (*uscale) * (1.f / 16129.f);   // (umax/127)*(1/127)
    __syncthreads();

    const i32x4 zeroi = {0, 0, 0, 0};
    int p = 0;
#pragma unroll 1
    for (int tl = 0; tl < CH; ++tl) {
        // xz: 64 B contiguous per lane, coalesced dwordx4 loads (fire early)
        const unsigned short* xb = xz + ((((size_t)tl * 8 + blk) * 8 + w) * 4 + quad) * 512 + l15 * 32;
        uint4 xq[4];
#pragma unroll
        for (int i2 = 0; i2 < 4; ++i2) xq[i2] = *(const uint4*)(xb + i2 * 8);
        const unsigned int* xd = (const unsigned int*)xq;

        // A fragments: 16 real rows from i8 h ping-pong
        const signed char* hb = hbuf[p];
        i32x4 Af[4];
#pragma unroll
        for (int kt = 0; kt < 4; ++kt)
            Af[kt] = *(const i32x4*)(hb + l15 * 272 + kt * 64 + quad * 16);

        i32x4 acc[8];
#pragma unroll
        for (int n = 0; n < 8; ++n) acc[n] = zeroi;
#pragma unroll
        for (int kt = 0; kt < 4; ++kt) {
            i32x4 a = Af[kt];
#pragma unroll
            for (int n = 0; n < 8; ++n)
                acc[n] = __builtin_amdgcn_mfma_i32_16x16x64_i8(a, Bf[n][kt], acc[n], 0, 0, 0);
        }

        // gates: lane owns rows quad*4+r, cols w*32+s*16+l15, all 4 gates local
        signed char* hw = hbuf[p ^ 1];
        unsigned short (*hs)[256] = hstage[(tl >> 1) & 1][tl & 1];
#pragma unroll
        for (int s = 0; s < 2; ++s)
#pragma unroll
            for (int r = 0; r < 4; ++r) {
                float zi = (float)acc[s][r]     * SUH + xzext(xd, (s) * 4 + r);
                float zf = (float)acc[2 + s][r] * SUH + xzext(xd, (2 + s) * 4 + r);
                float zg = (float)acc[4 + s][r] * SUH + xzext(xd, (4 + s) * 4 + r);
                float zo = (float)acc[6 + s][r] * SUH + xzext(xd, (6 + s) * 4 + r);
                int ci = s * 4 + r;
                float c = sigm(zf) * cst[ci] + sigm(zi) * tanh_(zg);
                cst[ci] = c;
                float h = sigm(zo) * tanh_(c);
                int rowh = quad * 4 + r, colh = w * 32 + s * 16 + l15;
                hw[rowh * 272 + colh] = (signed char)__float2int_rn(h * 127.f);
                hs[rowh][colh] = f2bf(h);
            }

        // flush previous 2-step group (coalesced, amortized vmcnt drain)
        if ((tl & 1) == 0 && tl > 0) {
            int fb = ((tl >> 1) & 1) ^ 1;
            int flat = tid * 16;
            int st = flat >> 12, rem = flat & 4095;
            int row = rem >> 8, colx = rem & 255;
            const unsigned short* srcp = &hstage[fb][st][row][colx];
            unsigned short* dst = hout + ((size_t)((t0 + tl - 2 + st) * 128 + blk * 16 + row)) * 256 + colx;
            *(uint4*)(dst) = *(const uint4*)(srcp);
            *(uint4*)(dst + 8) = *(const uint4*)(srcp + 8);
        }
        __syncthreads();
        p ^= 1;
    }
    {   // final flush: steps CH-2, CH-1
        int fb = ((CH - 1) >> 1) & 1;
        int flat = tid * 16;
        int st = flat >> 12, rem = flat & 4095;
        int row = rem >> 8, colx = rem & 255;
        const unsigned short* srcp = &hstage[fb][st][row][colx];
        unsigned short* dst = hout + ((size_t)((t0 + CH - 2 + st) * 128 + blk * 16 + row)) * 256 + colx;
        *(uint4*)(dst) = *(const uint4*)(srcp);
        *(uint4*)(dst + 8) = *(const uint4*)(srcp + 8);
    }
#pragma unroll
    for (int j = 0; j < 8; ++j)
        cstate[((size_t)blk * 512 + tid) * 8 + j] = cst[j];
}

// ---- Dense(tanh) + LayerNorm, one block per t (128 rows), full N=256 in regs ----
__global__ __launch_bounds__(256, 2) void k_dense_ln(
    const unsigned short* __restrict__ h2buf, const unsigned short* __restrict__ Wdt,
    const float* __restrict__ bd, const float* __restrict__ gamma,
    const float* __restrict__ beta, float* __restrict__ out) {
    const int t = blockIdx.x;
    const int tid = threadIdx.x;
    const int wave = tid >> 6, lane = tid & 63, quad = lane >> 4, l15 = lane & 15;
    const unsigned short* A = h2buf + (size_t)t * B_ * H_;
    const f32x4 zero = {0.f, 0.f, 0.f, 0.f};

    f32x4 acc[2][16];
#pragma unroll
    for (int m = 0; m < 2; ++m)
#pragma unroll
        for (int n = 0; n < 16; ++n) acc[m][n] = zero;

#pragma unroll
    for (int kt = 0; kt < 8; ++kt) {
        bf16x8 a[2];
#pragma unroll
        for (int m = 0; m < 2; ++m) {
            int row = wave * 32 + m * 16 + l15;
            a[m] = *(const bf16x8*)(A + (size_t)row * H_ + kt * 32 + quad * 8);
        }
#pragma unroll
        for (int n = 0; n < 16; ++n) {
            bf16x8 b = *(const bf16x8*)(Wdt + (size_t)(n * 16 + l15) * H_ + kt * 32 + quad * 8);
            acc[0][n] = __builtin_amdgcn_mfma_f32_16x16x32_bf16(a[0], b, acc[0][n], 0, 0, 0);
            acc[1][n] = __builtin_amdgcn_mfma_f32_16x16x32_bf16(a[1], b, acc[1][n], 0, 0, 0);
        }
    }

    float gm[16], bt[16], bdv[16];
#pragma unroll
    for (int n = 0; n < 16; ++n) {
        int c = n * 16 + l15;
        gm[n] = gamma[c]; bt[n] = beta[c]; bdv[n] = bd[c];
    }
#pragma unroll
    for (int m = 0; m < 2; ++m) {
#pragma unroll
        for (int r = 0; r < 4; ++r) {
            float v[16], s = 0.f, sq = 0.f;
#pragma unroll
            for (int n = 0; n < 16; ++n) {
                float x = tanh_(acc[m][n][r] + bdv[n]);
                v[n] = x; s += x; sq += x * x;
            }
#pragma unroll
            for (int off = 1; off < 16; off <<= 1) {
                s += __shfl_xor(s, off);
                sq += __shfl_xor(sq, off);
            }
            float mu = s * (1.f / 256.f);
            float var = sq * (1.f / 256.f) - mu * mu;
            float rs = rsqrtf(var + 1e-3f);
            int row = wave * 32 + m * 16 + quad * 4 + r;   // batch index
            float* po = out + (size_t)row * (T_ * H_) + (size_t)t * H_;
#pragma unroll
            for (int n = 0; n < 16; ++n)
                po[n * 16 + l15] = (v[n] - mu) * rs * gm[n] + bt[n];
        }
    }
}

extern "C" void kernel_launch(void* const* d_in, const int* in_sizes, int n_in,
                              void* d_out, int out_size, void* d_ws, size_t ws_size,
                              hipStream_t stream) {
    const float* x     = (const float*)d_in[0];
    const float* W0    = (const float*)d_in[1];
    const float* U0    = (const float*)d_in[2];
    const float* b0    = (const float*)d_in[3];
    const float* W1    = (const float*)d_in[4];
    const float* U1    = (const float*)d_in[5];
    const float* b1    = (const float*)d_in[6];
    const float* Wd    = (const float*)d_in[7];
    const float* bd    = (const float*)d_in[8];
    const float* gamma = (const float*)d_in[9];
    const float* beta  = (const float*)d_in[10];
    float* out = (float*)d_out;

    char* ws = (char*)d_ws;
    unsigned short* buf0 = (unsigned short*)(ws);                  // 32 MB: xbf, later h2
    unsigned short* xzs  = (unsigned short*)(ws + (32u << 20));    // 32 MB: per-chunk xz
    unsigned short* h1   = (unsigned short*)(ws + (64u << 20));    // 32 MB
    unsigned short* Wt0  = (unsigned short*)(ws + (96u << 20));            // 512 KB
    unsigned short* Wt1  = (unsigned short*)(ws + (96u << 20) + 524288);   // 512 KB
    signed char*    Ui0  = (signed char*)  (ws + (96u << 20) + 1048576);   // 256 KB
    signed char*    Ui1  = (signed char*)  (ws + (96u << 20) + 1310720);   // 256 KB
    unsigned short* Wdt  = (unsigned short*)(ws + (96u << 20) + 1572864);  // 128 KB
    float*          sc   = (float*)        (ws + (96u << 20) + 1703936);   // 2 slots
    float*          cbuf = (float*)        (ws + (96u << 20) + 1704448);   // 128 KB

    hipMemsetAsync(sc, 0, 64, stream);
    k_prep_x<<<16384, 256, 0, stream>>>(x, buf0);
    k_prep_w<<<1024, 256, 0, stream>>>(W0, Wt0);
    k_prep_w<<<1024, 256, 0, stream>>>(W1, Wt1);
    k_prep_wd<<<256, 256, 0, stream>>>(Wd, Wdt);
    k_umax<<<256, 256, 0, stream>>>(U0, sc);
    k_umax<<<256, 256, 0, stream>>>(U1, sc + 1);
    k_prep_u<<<1024, 256, 0, stream>>>(U0, sc, Ui0);
    k_prep_u<<<1024, 256, 0, stream>>>(U1, sc + 1, Ui1);

    for (int c = 0; c < 4; ++c) {
        k_gemm<<<CH * 4, 256, 0, stream>>>(buf0 + (size_t)c * CH * 32768, Wt0, b0, xzs);
        k_rec<<<RB, 512, 0, stream>>>(Ui0, xzs, sc, h1, cbuf, c * CH);
    }
    for (int c = 0; c < 4; ++c) {
        k_gemm<<<CH * 4, 256, 0, stream>>>(h1 + (size_t)c * CH * 32768, Wt1, b1, xzs);
        k_rec<<<RB, 512, 0, stream>>>(Ui1, xzs, sc + 1, buf0, cbuf, c * CH);
    }
    k_dense_ln<<<512, 256, 0, stream>>>(buf0, Wdt, bd, gamma, beta, out);
}